// Round 1
// baseline (566.697 us; speedup 1.0000x reference)
//
#include <hip/hip_runtime.h>

#define BATCH 16
#define HH 512
#define WW 512
#define CC 8
#define RR 4   // output rows per thread

__device__ __forceinline__ void fma4(float4& a, const float4 v, const float4 w) {
    a.x = fmaf(v.x, w.x, a.x);
    a.y = fmaf(v.y, w.y, a.y);
    a.z = fmaf(v.z, w.z, a.z);
    a.w = fmaf(v.w, w.w, a.w);
}

__global__ __launch_bounds__(256, 4) void dwconv5x5_kernel(
    const float* __restrict__ x, const float* __restrict__ kern,
    const float* __restrict__ bias, float* __restrict__ out)
{
    // ---- block decode with bijective XCD swizzle (gridDim.x = 4096, %8 == 0) ----
    int bid  = blockIdx.x;
    int per  = gridDim.x >> 3;                 // 512 blocks per XCD chunk
    int bid2 = (bid & 7) * per + (bid >> 3);   // contiguous row bands per XCD

    int wc = bid2 & 1;           // w chunk: 0 or 1
    int hb = (bid2 >> 1) & 127;  // h block: 0..127
    int b  = bid2 >> 8;          // batch:  0..15

    int tid = threadIdx.x;
    int w   = (wc << 8) + tid;   // 0..511
    int h0  = hb << 2;           // 0..508, this thread's 4 output rows h0..h0+3

    const float* xb = x + (size_t)b * (HH * WW * CC);

    // bias (uniform -> scalar loads)
    float4 bv0 = *(const float4*)(bias);
    float4 bv1 = *(const float4*)(bias + 4);

    float4 acc[RR][2];
    #pragma unroll
    for (int dh = 0; dh < RR; ++dh) { acc[dh][0] = bv0; acc[dh][1] = bv1; }

    bool wint = (w >= 2) && (w < WW - 2);

    // ---- sweep the 8 input rows h0-2 .. h0+5 ----
    #pragma unroll
    for (int i = 0; i < RR + 4; ++i) {
        int r = h0 - 2 + i;                  // block-uniform condition
        if (r < 0 || r >= HH) continue;

        const float* row = xb + ((size_t)r * WW + (w - 2)) * CC;

        float4 px[10];                       // pixels w-2 .. w+2, 2 float4 each
        if (wint) {
            #pragma unroll
            for (int j = 0; j < 10; ++j)
                px[j] = *(const float4*)(row + 4 * j);
        } else {
            #pragma unroll
            for (int p = 0; p < 5; ++p) {
                int wx = w - 2 + p;
                if ((unsigned)wx < (unsigned)WW) {
                    px[2 * p]     = *(const float4*)(row + 8 * p);
                    px[2 * p + 1] = *(const float4*)(row + 8 * p + 4);
                } else {
                    px[2 * p]     = make_float4(0.f, 0.f, 0.f, 0.f);
                    px[2 * p + 1] = make_float4(0.f, 0.f, 0.f, 0.f);
                }
            }
        }

        // each loaded input row feeds outputs dh with kh = i - dh in [0,4]
        #pragma unroll
        for (int dh = 0; dh < RR; ++dh) {
            int kh = i - dh;
            if (kh < 0 || kh > 4) continue;
            #pragma unroll
            for (int q = 0; q < 5; ++q) {
                const float* wp = kern + (kh * 5 + q) * 8;  // uniform -> s_load
                float4 w0 = *(const float4*)(wp);
                float4 w1 = *(const float4*)(wp + 4);
                fma4(acc[dh][0], px[2 * q],     w0);
                fma4(acc[dh][1], px[2 * q + 1], w1);
            }
        }
    }

    // ---- store 4 output pixels (2x dwordx4 each, coalesced) ----
    #pragma unroll
    for (int dh = 0; dh < RR; ++dh) {
        float* o = out + ((size_t)((b * HH + h0 + dh) * WW) + w) * CC;
        *(float4*)(o)     = acc[dh][0];
        *(float4*)(o + 4) = acc[dh][1];
    }
}

extern "C" void kernel_launch(void* const* d_in, const int* in_sizes, int n_in,
                              void* d_out, int out_size, void* d_ws, size_t ws_size,
                              hipStream_t stream) {
    const float* x    = (const float*)d_in[0];
    const float* kern = (const float*)d_in[1];
    const float* bias = (const float*)d_in[2];
    float* out        = (float*)d_out;

    dim3 grid(4096);   // 2 w-chunks * 128 h-blocks * 16 batches
    dim3 block(256);
    hipLaunchKernelGGL(dwconv5x5_kernel, grid, block, 0, stream, x, kern, bias, out);
}

// Round 2
// 565.989 us; speedup vs baseline: 1.0013x; 1.0013x over previous
//
#include <hip/hip_runtime.h>

#define HH 512
#define WW 512
#define CC 8
#define RR 4   // output rows per thread

typedef float f32x4 __attribute__((ext_vector_type(4)));

__device__ __forceinline__ float4 fma4(float4 a, const float4 v, const float4 w) {
    a.x = fmaf(v.x, w.x, a.x);
    a.y = fmaf(v.y, w.y, a.y);
    a.z = fmaf(v.z, w.z, a.z);
    a.w = fmaf(v.w, w.w, a.w);
    return a;
}

__global__ __launch_bounds__(256, 4) void dwconv5x5_kernel(
    const float* __restrict__ x, const float* __restrict__ kern,
    const float* __restrict__ bias, float* __restrict__ out)
{
    // ---- bijective XCD swizzle (gridDim.x = 4096, %8 == 0) ----
    int bid  = blockIdx.x;
    int per  = gridDim.x >> 3;                 // 512 blocks per XCD chunk
    int bid2 = (bid & 7) * per + (bid >> 3);   // contiguous (wc,hb) bands per XCD

    int wc = bid2 & 1;           // w chunk: 0 or 1
    int hb = (bid2 >> 1) & 127;  // h block: 0..127
    int b  = bid2 >> 8;          // batch:  0..15

    int tid = threadIdx.x;
    int w   = (wc << 8) + tid;   // 0..511
    int h0  = hb << 2;           // output rows h0..h0+3

    const float* xb = x + (size_t)b * (HH * WW * CC);

    float4 bv0 = *(const float4*)(bias);
    float4 bv1 = *(const float4*)(bias + 4);

    float4 acc[RR][2];
    #pragma unroll
    for (int dh = 0; dh < RR; ++dh) { acc[dh][0] = bv0; acc[dh][1] = bv1; }

    const bool wint = (w >= 2) && (w < WW - 2);

    // ---- sweep the 8 input rows h0-2 .. h0+5; load-and-FMA, no staging array ----
    #pragma unroll
    for (int i = 0; i < RR + 4; ++i) {
        const int r = h0 - 2 + i;            // block-uniform bounds check
        if (r < 0 || r >= HH) continue;

        const float* row = xb + ((size_t)r * WW + w) * CC;  // centered at w

        #pragma unroll
        for (int q = 0; q < 5; ++q) {
            float4 p0, p1;
            if (wint) {                      // wave-uniform for interior waves
                p0 = *(const float4*)(row + (q - 2) * CC);
                p1 = *(const float4*)(row + (q - 2) * CC + 4);
            } else {
                int wx = w + q - 2;
                if ((unsigned)wx < (unsigned)WW) {
                    p0 = *(const float4*)(row + (q - 2) * CC);
                    p1 = *(const float4*)(row + (q - 2) * CC + 4);
                } else {
                    p0 = make_float4(0.f, 0.f, 0.f, 0.f);
                    p1 = make_float4(0.f, 0.f, 0.f, 0.f);
                }
            }

            // input row r feeds output dh where kh = i - dh in [0,4]
            #pragma unroll
            for (int dh = 0; dh < RR; ++dh) {
                const int kh = i - dh;
                if (kh < 0 || kh > 4) continue;
                const float* wp = kern + (kh * 5 + q) * CC;  // uniform -> s_load
                float4 w0 = *(const float4*)(wp);
                float4 w1 = *(const float4*)(wp + 4);
                acc[dh][0] = fma4(acc[dh][0], p0, w0);
                acc[dh][1] = fma4(acc[dh][1], p1, w1);
            }
        }
    }

    // ---- non-temporal coalesced stores (output has no reuse; keep L2 for halo) ----
    #pragma unroll
    for (int dh = 0; dh < RR; ++dh) {
        float* o = out + ((size_t)((b * HH + h0 + dh) * WW) + w) * CC;
        __builtin_nontemporal_store(*(const f32x4*)&acc[dh][0], (f32x4*)o);
        __builtin_nontemporal_store(*(const f32x4*)&acc[dh][1], (f32x4*)(o + 4));
    }
}

extern "C" void kernel_launch(void* const* d_in, const int* in_sizes, int n_in,
                              void* d_out, int out_size, void* d_ws, size_t ws_size,
                              hipStream_t stream) {
    const float* x    = (const float*)d_in[0];
    const float* kern = (const float*)d_in[1];
    const float* bias = (const float*)d_in[2];
    float* out        = (float*)d_out;

    dim3 grid(4096);   // 2 w-chunks * 128 h-blocks * 16 batches
    dim3 block(256);
    hipLaunchKernelGGL(dwconv5x5_kernel, grid, block, 0, stream, x, kern, bias, out);
}

// Round 6
// 376.901 us; speedup vs baseline: 1.5036x; 1.5017x over previous
//
#include <hip/hip_runtime.h>

#define HH 512
#define WW 512
#define CC 8
#define SROWS 16   // output rows per thread (column sweep segment)

__device__ __forceinline__ float4 fma4(float4 a, const float4 v, const float4 w) {
    a.x = fmaf(v.x, w.x, a.x);
    a.y = fmaf(v.y, w.y, a.y);
    a.z = fmaf(v.z, w.z, a.z);
    a.w = fmaf(v.w, w.w, a.w);
    return a;
}

__global__ __launch_bounds__(256) void dwconv5x5_kernel(
    const float* __restrict__ x, const float* __restrict__ kern,
    const float* __restrict__ bias, float* __restrict__ out)
{
    // ---- bijective XCD swizzle (gridDim.x = 1024, %8 == 0) ----
    // linear id lin = b*64 + seg*2 + wc ; 128 consecutive lin per XCD
    // => each XCD owns exactly 2 complete batches: h-halo sharing is XCD-local.
    int bid = blockIdx.x;
    int per = gridDim.x >> 3;                  // 128
    int lin = (bid & 7) * per + (bid >> 3);

    int wc  = lin & 1;           // w chunk 0..1
    int seg = (lin >> 1) & 31;   // h segment 0..31  (32 segs * 16 rows = 512)
    int b   = lin >> 6;          // batch 0..15

    int w  = (wc << 8) + threadIdx.x;   // 0..511
    int y0 = seg << 4;                  // first output row of segment

    const float* xb = x + (size_t)b * (HH * WW * CC);

    float4 bv0 = *(const float4*)(bias);
    float4 bv1 = *(const float4*)(bias + 4);

    const bool wint = (w >= 2) && (w < WW - 2);

    #pragma unroll 2
    for (int yy = 0; yy < SROWS; ++yy) {
        const int y = y0 + yy;

        float4 a0 = bv0, a1 = bv1;

        #pragma unroll
        for (int kh = 0; kh < 5; ++kh) {
            const int r = y - 2 + kh;
            if (r < 0 || r >= HH) continue;   // uniform scalar branch

            const float* row = xb + ((size_t)r * WW + w) * CC;

            if (wint) {
                #pragma unroll
                for (int q = 0; q < 5; ++q) {
                    float4 p0 = *(const float4*)(row + (q - 2) * CC);
                    float4 p1 = *(const float4*)(row + (q - 2) * CC + 4);
                    const float* wp = kern + (kh * 5 + q) * CC;   // uniform -> s_load
                    a0 = fma4(a0, p0, *(const float4*)(wp));
                    a1 = fma4(a1, p1, *(const float4*)(wp + 4));
                }
            } else {
                #pragma unroll
                for (int q = 0; q < 5; ++q) {
                    int wx = w + q - 2;
                    float4 p0, p1;
                    if ((unsigned)wx < (unsigned)WW) {
                        p0 = *(const float4*)(row + (q - 2) * CC);
                        p1 = *(const float4*)(row + (q - 2) * CC + 4);
                    } else {
                        p0 = make_float4(0.f, 0.f, 0.f, 0.f);
                        p1 = make_float4(0.f, 0.f, 0.f, 0.f);
                    }
                    const float* wp = kern + (kh * 5 + q) * CC;
                    a0 = fma4(a0, p0, *(const float4*)(wp));
                    a1 = fma4(a1, p1, *(const float4*)(wp + 4));
                }
            }
        }

        // plain coalesced stores; the wave's two dwordx4 stores per row cover
        // a contiguous 2 KiB span -> full-line write-combining in L2
        float* o = out + ((size_t)((b * HH + y) * WW) + w) * CC;
        *(float4*)(o)     = a0;
        *(float4*)(o + 4) = a1;
    }
}

extern "C" void kernel_launch(void* const* d_in, const int* in_sizes, int n_in,
                              void* d_out, int out_size, void* d_ws, size_t ws_size,
                              hipStream_t stream) {
    const float* x    = (const float*)d_in[0];
    const float* kern = (const float*)d_in[1];
    const float* bias = (const float*)d_in[2];
    float* out        = (float*)d_out;

    dim3 grid(1024);   // 16 batches * 32 segments * 2 w-chunks
    dim3 block(256);
    hipLaunchKernelGGL(dwconv5x5_kernel, grid, block, 0, stream, x, kern, bias, out);
}